// Round 2
// baseline (1660.085 us; speedup 1.0000x reference)
//
#include <hip/hip_runtime.h>
#include <stdint.h>
#include <math.h>

#define V 30000
#define E 60000
#define G 1200
#define D 64
#define NODE_IN 74
#define EDGE_IN 12
#define EH 128
#define N_MP 6
#define N_S2S 6

#define NBLK ((E + 63) / 64)   // 938 edge-tiles of 64

typedef short bf16x8 __attribute__((ext_vector_type(8)));
typedef float f32x4 __attribute__((ext_vector_type(4)));

__device__ __forceinline__ float sigmoidf_(float x) {
    return 1.0f / (1.0f + __expf(-x));
}
__device__ __forceinline__ float tanhf_(float x) {
    float t = __expf(-2.0f * fabsf(x));
    float r = (1.0f - t) / (1.0f + t);
    return copysignf(r, x);
}
__device__ __forceinline__ uint16_t f2bf(float f) {
    uint32_t u = __float_as_uint(f);
    u += 0x7fffu + ((u >> 16) & 1u);
    return (uint16_t)(u >> 16);
}

// ---------------- generic zero-fill ----------------
__global__ void k_zero(float* __restrict__ p, int n4) {
    int i = blockIdx.x * blockDim.x + threadIdx.x;
    if (i < n4) ((float4*)p)[i] = make_float4(0.f, 0.f, 0.f, 0.f);
}

// ---------------- h0 = relu(node_feats @ proj_W + proj_b) ----------------
__global__ void k_node_proj(const float* __restrict__ nf, const float* __restrict__ W,
                            const float* __restrict__ b, float* __restrict__ h) {
    int wave = threadIdx.x >> 6, lane = threadIdx.x & 63;
    int v = blockIdx.x * 4 + wave;           // V % 4 == 0
    __shared__ float xs[4][NODE_IN];
    xs[wave][lane] = nf[(size_t)v * NODE_IN + lane];
    if (lane + 64 < NODE_IN) xs[wave][lane + 64] = nf[(size_t)v * NODE_IN + lane + 64];
    __syncthreads();
    float acc = b[lane];
    #pragma unroll
    for (int i = 0; i < NODE_IN; ++i) acc = fmaf(xs[wave][i], W[i * D + lane], acc);
    h[(size_t)v * D + lane] = fmaxf(acc, 0.0f);
}

// ---------------- HedgeP = bf16-permuted relu(edge_feats @ eW1 + eb1) ----------------
// Layout: chunk(b, w, kt) of 512 elems; elem (quad, m, j) = Hedge[e=b*64+w*16+m][k=kt*32+quad*8+j]
__global__ void k_edge_hidden(const float* __restrict__ ef, const float* __restrict__ W1,
                              const float* __restrict__ b1, uint16_t* __restrict__ HedgeP) {
    int e = blockIdx.x;
    int j = threadIdx.x;                      // 128 threads
    __shared__ float xs[EDGE_IN];
    if (j < EDGE_IN) xs[j] = ef[(size_t)e * EDGE_IN + j];
    __syncthreads();
    float acc = b1[j];
    #pragma unroll
    for (int i = 0; i < EDGE_IN; ++i) acc = fmaf(xs[i], W1[i * EH + j], acc);
    float r = fmaxf(acc, 0.0f);
    int b = e >> 6, w = (e >> 4) & 3, m = e & 15;
    int kt = j >> 5, quad = (j >> 3) & 3, jj = j & 7;
    size_t off = ((((size_t)(b * 4 + w) * 4 + kt) * 4 + quad) * 16 + m) * 8 + jj;
    HedgeP[off] = f2bf(r);
}

// ---------------- W2p: eW2 (128 x 4096 fp32) -> bf16 B-frag-permuted ----------------
// chunk(i, kt, nt) of 512; elem (quad, n0, j) = eW2[k=kt*32+quad*8+j][i*64+nt*16+n0]
__global__ void k_prep_w2(const float* __restrict__ eW2, uint16_t* __restrict__ W2p) {
    int idx = blockIdx.x * 256 + threadIdx.x;           // 524288 total
    int j = idx & 7;
    int n0 = (idx >> 3) & 15;
    int quad = (idx >> 7) & 3;
    int nt = (idx >> 9) & 3;
    int kt = (idx >> 11) & 3;
    int i = idx >> 13;
    int k = kt * 32 + quad * 8 + j;
    int col = i * 64 + nt * 16 + n0;
    W2p[idx] = f2bf(eW2[(size_t)k * 4096 + col]);
}

// ---------------- fused We-recompute + message + scatter ----------------
// Per block: 64 edges, 4 waves. m_e[o] = sum_i h_src[i] * (C_i[e][o] + b2[i][o]),
// C_i = Hedge_tile(64x128) @ W2[:, i*64 : i*64+64]   (bf16 MFMA 16x16x32)
__global__ __launch_bounds__(256) void k_message_mfma(
    const uint16_t* __restrict__ HedgeP, const uint16_t* __restrict__ W2p,
    const float* __restrict__ eb2, const float* __restrict__ h,
    const int* __restrict__ src, const int* __restrict__ dst,
    float* __restrict__ agg) {
    const int b = blockIdx.x;
    const int t = threadIdx.x;
    const int w = t >> 6, lane = t & 63;
    const int quad = lane >> 4, n0 = lane & 15;

    __shared__ float Hs[64][66];              // +2 pad: column reads hit distinct banks
    __shared__ float B2s[64][64];             // b2 as [i][o]
    __shared__ int srcv[64], dstv[64];

    if (t < 64) {
        int e = b * 64 + t;
        int sv = 0, dv = -1;
        if (e < E) { sv = src[e]; dv = dst[e]; }
        srcv[t] = sv; dstv[t] = dv;
    }
    for (int idx = t; idx < 4096; idx += 256) ((float*)B2s)[idx] = eb2[idx];
    __syncthreads();
    for (int idx = t; idx < 4096; idx += 256) {
        int e = idx >> 6, c = idx & 63;
        Hs[e][c] = h[(size_t)srcv[e] * 64 + c];
    }
    // A-fragments: i-independent, 4 K-tiles of 32
    bf16x8 Af[4];
    {
        const uint16_t* base = HedgeP + (size_t)(b * 4 + w) * 4 * 512;
        #pragma unroll
        for (int kt = 0; kt < 4; ++kt)
            Af[kt] = *(const bf16x8*)(base + kt * 512 + lane * 8);
    }
    __syncthreads();

    f32x4 acc[4] = {};                        // [nt], rows = quad*4+reg
    const int row0 = w * 16 + quad * 4;
    for (int i = 0; i < 64; ++i) {
        const uint16_t* wb = W2p + (size_t)i * 8192;   // i*16 chunks*512
        f32x4 tmp[4] = {};
        #pragma unroll
        for (int kt = 0; kt < 4; ++kt) {
            #pragma unroll
            for (int nt = 0; nt < 4; ++nt) {
                bf16x8 Bf = *(const bf16x8*)(wb + (size_t)(kt * 4 + nt) * 512 + lane * 8);
                tmp[nt] = __builtin_amdgcn_mfma_f32_16x16x32_bf16(Af[kt], Bf, tmp[nt], 0, 0, 0);
            }
        }
        float h0 = Hs[row0 + 0][i], h1 = Hs[row0 + 1][i];
        float h2 = Hs[row0 + 2][i], h3 = Hs[row0 + 3][i];
        #pragma unroll
        for (int nt = 0; nt < 4; ++nt) {
            float bv = B2s[i][nt * 16 + n0];
            acc[nt][0] = fmaf(h0, tmp[nt][0] + bv, acc[nt][0]);
            acc[nt][1] = fmaf(h1, tmp[nt][1] + bv, acc[nt][1]);
            acc[nt][2] = fmaf(h2, tmp[nt][2] + bv, acc[nt][2]);
            acc[nt][3] = fmaf(h3, tmp[nt][3] + bv, acc[nt][3]);
        }
    }
    #pragma unroll
    for (int reg = 0; reg < 4; ++reg) {
        int d = dstv[row0 + reg];
        if (d >= 0) {
            #pragma unroll
            for (int nt = 0; nt < 4; ++nt)
                atomicAdd(agg + (size_t)d * 64 + nt * 16 + n0, acc[nt][reg]);
        }
    }
}

// ---------------- GRU cell over all nodes (x = relu(agg + conv_b)) ----------------
#define GRU_NPB 8
__global__ __launch_bounds__(192) void k_gru(const float* __restrict__ agg,
                                             const float* __restrict__ convb,
                                             const float* __restrict__ Wih,
                                             const float* __restrict__ bih,
                                             const float* __restrict__ Whh,
                                             const float* __restrict__ bhh,
                                             float* __restrict__ hcur) {
    int v0 = blockIdx.x * GRU_NPB;            // V % 8 == 0
    int j = threadIdx.x;                       // 0..191
    __shared__ float xs[GRU_NPB][64];
    __shared__ float hh[GRU_NPB][64];
    __shared__ float gg[GRU_NPB][384];
    for (int idx = j; idx < GRU_NPB * 64; idx += 192) {
        int n = idx >> 6, d = idx & 63;
        int v = v0 + n;
        xs[n][d] = fmaxf(agg[(size_t)v * 64 + d] + convb[d], 0.f);
        hh[n][d] = hcur[(size_t)v * 64 + d];
    }
    __syncthreads();
    float bi = bih[j], bh = bhh[j];
    float gi[GRU_NPB], gh[GRU_NPB];
    #pragma unroll
    for (int n = 0; n < GRU_NPB; ++n) { gi[n] = bi; gh[n] = bh; }
    #pragma unroll 8
    for (int i = 0; i < 64; ++i) {
        float w1 = Wih[i * 192 + j];
        float w2 = Whh[i * 192 + j];
        #pragma unroll
        for (int n = 0; n < GRU_NPB; ++n) {
            gi[n] = fmaf(xs[n][i], w1, gi[n]);
            gh[n] = fmaf(hh[n][i], w2, gh[n]);
        }
    }
    #pragma unroll
    for (int n = 0; n < GRU_NPB; ++n) { gg[n][j] = gi[n]; gg[n][192 + j] = gh[n]; }
    __syncthreads();
    for (int idx = j; idx < GRU_NPB * 64; idx += 192) {
        int n = idx >> 6, d = idx & 63;
        int v = v0 + n;
        float ir = gg[n][d], iz = gg[n][64 + d], inn = gg[n][128 + d];
        float hr = gg[n][192 + d], hz = gg[n][256 + d], hn = gg[n][320 + d];
        float r = sigmoidf_(ir + hr);
        float z = sigmoidf_(iz + hz);
        float nn = tanhf_(inn + r * hn);
        hcur[(size_t)v * 64 + d] = (1.f - z) * nn + z * hh[n][d];
    }
}

// ---------------- segment start offsets from sorted gids ----------------
__global__ void k_seg(const int* __restrict__ gids, int* __restrict__ start) {
    int v = blockIdx.x * blockDim.x + threadIdx.x;
    if (v > V) return;
    int cur = (v < V) ? gids[v] : G;
    int prev = (v == 0) ? -1 : gids[v - 1];
    for (int g = prev + 1; g <= cur; ++g) start[g] = v;
}

// ---------------- Set2Set 3-layer LSTM step: q_star -> q ----------------
#define LS_GPB 8
__global__ __launch_bounds__(256) void k_lstm(const float* __restrict__ q_star,
    const float* __restrict__ Wih0, const float* __restrict__ bih0,
    const float* __restrict__ Whh0, const float* __restrict__ bhh0,
    const float* __restrict__ Wih1, const float* __restrict__ bih1,
    const float* __restrict__ Whh1, const float* __restrict__ bhh1,
    const float* __restrict__ Wih2, const float* __restrict__ bih2,
    const float* __restrict__ Whh2, const float* __restrict__ bhh2,
    float* __restrict__ hs, float* __restrict__ cs, float* __restrict__ q) {
    int g0 = blockIdx.x * LS_GPB;             // G % 8 == 0
    int j = threadIdx.x;                       // 0..255
    __shared__ float xs[LS_GPB][128];
    __shared__ float hl[LS_GPB][64];
    __shared__ float gates[LS_GPB][256];
    for (int idx = j; idx < LS_GPB * 128; idx += 256) {
        int n = idx >> 7, d = idx & 127;
        xs[n][d] = q_star[(size_t)(g0 + n) * 128 + d];
    }
    const float* Wihs[3] = {Wih0, Wih1, Wih2};
    const float* bihs[3] = {bih0, bih1, bih2};
    const float* Whhs[3] = {Whh0, Whh1, Whh2};
    const float* bhhs[3] = {bhh0, bhh1, bhh2};
    const int dins[3] = {128, 64, 64};
    for (int l = 0; l < 3; ++l) {
        for (int idx = j; idx < LS_GPB * 64; idx += 256) {
            int n = idx >> 6, d = idx & 63;
            hl[n][d] = hs[(size_t)l * G * 64 + (size_t)(g0 + n) * 64 + d];
        }
        __syncthreads();
        float acc[LS_GPB];
        float bsum = bihs[l][j] + bhhs[l][j];
        #pragma unroll
        for (int n = 0; n < LS_GPB; ++n) acc[n] = bsum;
        const float* Wih = Wihs[l];
        int din = dins[l];
        for (int i = 0; i < din; ++i) {
            float w = Wih[i * 256 + j];
            #pragma unroll
            for (int n = 0; n < LS_GPB; ++n) acc[n] = fmaf(xs[n][i], w, acc[n]);
        }
        const float* Whh = Whhs[l];
        for (int i = 0; i < 64; ++i) {
            float w = Whh[i * 256 + j];
            #pragma unroll
            for (int n = 0; n < LS_GPB; ++n) acc[n] = fmaf(hl[n][i], w, acc[n]);
        }
        #pragma unroll
        for (int n = 0; n < LS_GPB; ++n) gates[n][j] = acc[n];
        __syncthreads();
        for (int idx = j; idx < LS_GPB * 64; idx += 256) {
            int n = idx >> 6, d = idx & 63;
            float ig = gates[n][d], fg = gates[n][64 + d];
            float gt = gates[n][128 + d], og = gates[n][192 + d];
            size_t off = (size_t)l * G * 64 + (size_t)(g0 + n) * 64 + d;
            float c = sigmoidf_(fg) * cs[off] + sigmoidf_(ig) * tanhf_(gt);
            float hnew = sigmoidf_(og) * tanhf_(c);
            cs[off] = c;
            hs[off] = hnew;
            xs[n][d] = hnew;
            if (l == 2) q[(size_t)(g0 + n) * 64 + d] = hnew;
        }
        __syncthreads();
    }
}

// ---------------- attention softmax + readout -> q_star ----------------
__global__ void k_attention(const float* __restrict__ h, const float* __restrict__ q,
                            const int* __restrict__ segs, float* __restrict__ q_star) {
    int g = blockIdx.x;
    int lane = threadIdx.x;                   // 64 threads = 1 wave
    int vs = segs[g], ve = segs[g + 1];
    float qv = q[(size_t)g * 64 + lane];
    float m = -INFINITY;
    for (int v = vs; v < ve; ++v) {
        float p = h[(size_t)v * 64 + lane] * qv;
        #pragma unroll
        for (int off = 32; off > 0; off >>= 1) p += __shfl_xor(p, off, 64);
        m = fmaxf(m, p);
    }
    float s = 0.f, acc = 0.f;
    for (int v = vs; v < ve; ++v) {
        float hv = h[(size_t)v * 64 + lane];
        float p = hv * qv;
        #pragma unroll
        for (int off = 32; off > 0; off >>= 1) p += __shfl_xor(p, off, 64);
        float ex = __expf(p - m);
        s += ex;
        acc = fmaf(hv, ex, acc);
    }
    float r = (ve > vs) ? acc / s : 0.f;
    q_star[(size_t)g * 128 + lane] = qv;
    q_star[(size_t)g * 128 + 64 + lane] = r;
}

// ---------------- final MLPs ----------------
__global__ void k_final(const float* __restrict__ q_star,
                        const float* __restrict__ pW, const float* __restrict__ pb,
                        const float* __restrict__ qW1, const float* __restrict__ qb1,
                        const float* __restrict__ qW2, const float* __restrict__ qb2,
                        const float* __restrict__ qW3, const float* __restrict__ qb3,
                        float* __restrict__ out) {
    int g = blockIdx.x;
    int lane = threadIdx.x;                   // 64 threads
    __shared__ float buf[128];
    buf[lane] = q_star[(size_t)g * 128 + lane];
    buf[64 + lane] = q_star[(size_t)g * 128 + 64 + lane];
    __syncthreads();
    float y = pb[lane];
    #pragma unroll 8
    for (int i = 0; i < 128; ++i) y = fmaf(buf[i], pW[i * 64 + lane], y);
    y = fmaxf(y, 0.f);
    __syncthreads(); buf[lane] = y; __syncthreads();
    float y1 = qb1[lane];
    #pragma unroll 8
    for (int i = 0; i < 64; ++i) y1 = fmaf(buf[i], qW1[i * 64 + lane], y1);
    y1 = fmaxf(y1, 0.f);
    __syncthreads(); buf[lane] = y1; __syncthreads();
    float y2 = qb2[lane];
    #pragma unroll 8
    for (int i = 0; i < 64; ++i) y2 = fmaf(buf[i], qW2[i * 64 + lane], y2);
    y2 = fmaxf(y2, 0.f);
    float p = y2 * qW3[lane];
    #pragma unroll
    for (int off = 32; off > 0; off >>= 1) p += __shfl_xor(p, off, 64);
    if (lane == 0) out[g] = p + qb3[0];
}

extern "C" void kernel_launch(void* const* d_in, const int* in_sizes, int n_in,
                              void* d_out, int out_size, void* d_ws, size_t ws_size,
                              hipStream_t stream) {
    const float* node_feats = (const float*)d_in[0];
    const float* edge_feats = (const float*)d_in[1];
    const int*   src        = (const int*)d_in[2];
    const int*   dst        = (const int*)d_in[3];
    const int*   gids       = (const int*)d_in[4];
    const float* proj_W     = (const float*)d_in[5];
    const float* proj_b     = (const float*)d_in[6];
    const float* eW1        = (const float*)d_in[7];
    const float* eb1        = (const float*)d_in[8];
    const float* eW2        = (const float*)d_in[9];
    const float* eb2        = (const float*)d_in[10];
    const float* conv_b     = (const float*)d_in[11];
    const float* gru_Wih    = (const float*)d_in[12];
    const float* gru_bih    = (const float*)d_in[13];
    const float* gru_Whh    = (const float*)d_in[14];
    const float* gru_bhh    = (const float*)d_in[15];
    const float* pW         = (const float*)d_in[16];
    const float* pb         = (const float*)d_in[17];
    const float* qW1        = (const float*)d_in[18];
    const float* qb1        = (const float*)d_in[19];
    const float* qW2        = (const float*)d_in[20];
    const float* qb2        = (const float*)d_in[21];
    const float* qW3        = (const float*)d_in[22];
    const float* qb3        = (const float*)d_in[23];
    const float* lWih0 = (const float*)d_in[24]; const float* lbih0 = (const float*)d_in[25];
    const float* lWhh0 = (const float*)d_in[26]; const float* lbhh0 = (const float*)d_in[27];
    const float* lWih1 = (const float*)d_in[28]; const float* lbih1 = (const float*)d_in[29];
    const float* lWhh1 = (const float*)d_in[30]; const float* lbhh1 = (const float*)d_in[31];
    const float* lWih2 = (const float*)d_in[32]; const float* lbih2 = (const float*)d_in[33];
    const float* lWhh2 = (const float*)d_in[34]; const float* lbhh2 = (const float*)d_in[35];

    // ---- workspace layout (total ~34.5 MB) ----
    char* ws = (char*)d_ws;
    uint16_t* HedgeP = (uint16_t*)(ws + 0);                      // 15,368,192 B (938*64 rows)
    uint16_t* W2p    = (uint16_t*)(ws + 15368192);               //  1,048,576 B
    float*    hcur   = (float*)(ws + 16416768);                  //  7,680,000 B
    float*    agg    = (float*)(ws + 24096768);                  //  7,680,000 B
    float*    q_star = (float*)(ws + 31776768);                  //    614,400 B
    float*    hsbuf  = (float*)(ws + 32391168);                  //    921,600 B
    float*    csbuf  = (float*)(ws + 33312768);                  //    921,600 B
    float*    qbuf   = (float*)(ws + 34234368);                  //    307,200 B
    int*      segs   = (int*)(ws + 34541568);                    //      4,804 B

    // --- one-time phase ---
    k_node_proj<<<V / 4, 256, 0, stream>>>(node_feats, proj_W, proj_b, hcur);
    k_edge_hidden<<<E, 128, 0, stream>>>(edge_feats, eW1, eb1, HedgeP);
    k_prep_w2<<<2048, 256, 0, stream>>>(eW2, W2p);
    k_seg<<<(V + 1 + 255) / 256, 256, 0, stream>>>(gids, segs);
    // zero q_star + hs + cs (contiguous: 2,457,600 B = 614,400 floats = 153,600 float4)
    k_zero<<<(153600 + 255) / 256, 256, 0, stream>>>(q_star, 153600);

    // --- message passing ---
    for (int t = 0; t < N_MP; ++t) {
        k_zero<<<(480000 + 255) / 256, 256, 0, stream>>>(agg, 480000);  // V*64/4
        k_message_mfma<<<NBLK, 256, 0, stream>>>(HedgeP, W2p, eb2, hcur, src, dst, agg);
        k_gru<<<V / GRU_NPB, 192, 0, stream>>>(agg, conv_b, gru_Wih, gru_bih,
                                               gru_Whh, gru_bhh, hcur);
    }

    // --- Set2Set ---
    for (int s = 0; s < N_S2S; ++s) {
        k_lstm<<<G / LS_GPB, 256, 0, stream>>>(q_star,
            lWih0, lbih0, lWhh0, lbhh0,
            lWih1, lbih1, lWhh1, lbhh1,
            lWih2, lbih2, lWhh2, lbhh2,
            hsbuf, csbuf, qbuf);
        k_attention<<<G, 64, 0, stream>>>(hcur, qbuf, segs, q_star);
    }

    // --- predict MLPs ---
    k_final<<<G, 64, 0, stream>>>(q_star, pW, pb, qW1, qb1, qW2, qb2, qW3, qb3,
                                  (float*)d_out);
}